// Round 16
// baseline (275.678 us; speedup 1.0000x reference)
//
#include <hip/hip_runtime.h>
#include <cstdint>
#include <cstddef>

typedef unsigned short u16;
typedef __attribute__((ext_vector_type(8))) __bf16 bf16x8;
typedef __attribute__((ext_vector_type(4))) unsigned short u16x4;
typedef __attribute__((ext_vector_type(8))) unsigned short u16x8;
typedef __attribute__((ext_vector_type(4))) float f32x4;

#define NTOK 197
#define TT   209
#define CDIM 768
#define NH   12
#define HD   64
#define BATCH 64
#define GM (BATCH*TT)   // 13376
#define VTP 224         // padded T stride for transposed V
#define NQKV 2304

__device__ __forceinline__ float bf2f(u16 u){ return __uint_as_float(((unsigned)u)<<16); }
__device__ __forceinline__ u16 f2bf(float f){
  unsigned x = __float_as_uint(f);
  return (u16)((x + 0x7FFFu + ((x>>16)&1u)) >> 16);   // RNE; inputs finite
}

__device__ __forceinline__ void gll16(const void* g, void* l){
  __builtin_amdgcn_global_load_lds((const __attribute__((address_space(1))) void*)g,
                                   (__attribute__((address_space(3))) void*)l,
                                   16, 0, 0);
}

__device__ __forceinline__ float wsum64(float v){
  #pragma unroll
  for (int o = 32; o > 0; o >>= 1) v += __shfl_xor(v, o, 64);
  return v;
}

// ---------------------------------------------------------------- dtype detect
__global__ __launch_bounds__(64) void detect_kernel(const u16* __restrict__ x, int* flag){
  const int lane = threadIdx.x;
  float mx = 0.f;
  #pragma unroll
  for (int i = 0; i < 16; i++) {
    float v = fabsf(bf2f(x[i*64 + lane]));
    if (!(v < 1e30f)) v = 1e30f;
    mx = fmaxf(mx, v);
  }
  #pragma unroll
  for (int o = 32; o; o >>= 1) mx = fmaxf(mx, __shfl_xor(mx, o, 64));
  if (lane == 0) *flag = (mx < 1e5f) ? 1 : 0;   // 1 = device buffers are bf16
}

// ---------------------------------------------------------------- fused convert
struct CA { const void* in[10]; void* out[10]; int n[10]; };
__global__ __launch_bounds__(256) void convert_all_kernel(CA a, const int* __restrict__ flag){
  const int seg = blockIdx.y;
  if (seg == 1 || seg == 3) return;
  const int f = *flag;
  if (seg == 0 && f) return;
  const int n = a.n[seg];
  const int n4 = n >> 2;
  u16* out = (u16*)a.out[seg];
  if (f) {
    const u16x4* in = (const u16x4*)a.in[seg];
    for (int i = blockIdx.x*256 + threadIdx.x; i < n4; i += gridDim.x*256)
      ((u16x4*)out)[i] = in[i];
  } else {
    const f32x4* in = (const f32x4*)a.in[seg];
    for (int i = blockIdx.x*256 + threadIdx.x; i < n4; i += gridDim.x*256){
      f32x4 v = in[i];
      u16x4 o;
      #pragma unroll
      for (int j=0;j<4;j++) o[j] = f2bf(v[j]);
      ((u16x4*)out)[i] = o;
    }
  }
  if (blockIdx.x == 0 && (int)threadIdx.x < (n & 3)) {
    int i = (n4 << 2) + threadIdx.x;
    out[i] = f ? ((const u16*)a.in[seg])[i] : f2bf(((const float*)a.in[seg])[i]);
  }
}

// ---------------------------------------------------------------- fused transpose (+convert)
__global__ __launch_bounds__(256) void transpose2_kernel(
    const void* __restrict__ w1, const void* __restrict__ w2,
    u16* __restrict__ o1, u16* __restrict__ o2, const int* __restrict__ flag)
{
  __shared__ u16 lds[64][66];
  const int f = *flag;
  int bid = blockIdx.x;
  const void* in; u16* out; int K, N, tx, ty;
  if (bid < 432) { in = w1; out = o1; K = CDIM; N = NQKV; tx = bid % 36; ty = bid / 36; }
  else { bid -= 432; in = w2; out = o2; K = CDIM; N = CDIM; tx = bid % 12; ty = bid / 12; }
  const int n0 = tx*64, k0 = ty*64;
  const int c = threadIdx.x & 63, r0 = threadIdx.x >> 6;
  #pragma unroll
  for (int i=0;i<16;i++) {
    int r = i*4 + r0;
    size_t idx = (size_t)(k0+r)*N + n0 + c;
    lds[r][c] = f ? ((const u16*)in)[idx] : f2bf(((const float*)in)[idx]);
  }
  __syncthreads();
  #pragma unroll
  for (int i=0;i<16;i++) {
    int r = i*4 + r0;
    out[(size_t)(n0+r)*K + k0 + c] = lds[c][r];
  }
}

// ---------------------------------------------------------------- mean (ht phase 1)
// grid (BATCH, 3): block (b,s) computes f32 column-mean for cols s*256..+255.
__global__ __launch_bounds__(256) void mean_kernel(
    const u16* __restrict__ xc, const void* __restrict__ xr,
    float* __restrict__ mbuf, const int* __restrict__ flag)
{
  const int b = blockIdx.x, s = blockIdx.y;
  const int tid = threadIdx.x;
  const int f = *flag;
  const u16* x = f ? (const u16*)xr : xc;
  const u16* xp = x + (size_t)b*NTOK*CDIM + s*256 + tid;
  float cs = 0.f;
  for (int n = 0; n < NTOK; n++) cs += bf2f(xp[(size_t)n*CDIM]);
  mbuf[(size_t)b*CDIM + s*256 + tid] = cs * (1.0f/(float)NTOK);
}

// ---------------------------------------------------------------- ht matvec+LN (phase 2)
// grid (BATCH, NH) = 768 blocks, 256 thr: block (b,h) computes ht row b*NH+h.
// 64-f32 mean slice in LDS; matvec with coalesced u16 loads; LN over each
// 64-col group (= one wave, wsum64) + exact GELU + pos.
__global__ __launch_bounds__(256) void htmm_kernel(
    const float* __restrict__ mbuf,
    const u16* __restrict__ htw, const u16* __restrict__ htb,
    const u16* __restrict__ lng, const u16* __restrict__ lnb,
    const u16* __restrict__ pos, u16* __restrict__ ht)
{
  const int b = blockIdx.x, h = blockIdx.y;
  const int tid = threadIdx.x;
  __shared__ float msh[64];
  if (tid < 64) msh[tid] = mbuf[(size_t)b*CDIM + h*HD + tid];
  __syncthreads();

  float v0 = bf2f(htb[tid]), v1 = bf2f(htb[tid+256]), v2 = bf2f(htb[tid+512]);
  for (int d = 0; d < HD; d++) {
    const float md = msh[d];
    const u16* wr = htw + (size_t)d*CDIM;
    v0 += md * bf2f(wr[tid]);
    v1 += md * bf2f(wr[tid+256]);
    v2 += md * bf2f(wr[tid+512]);
  }
  const float gam = bf2f(lng[tid & 63]), bet = bf2f(lnb[tid & 63]);
  float vv[3] = {v0, v1, v2};
  #pragma unroll
  for (int ch = 0; ch < 3; ch++) {
    int c = ch*256 + tid;
    float mu = wsum64(vv[ch]) * (1.0f/(float)HD);
    float dv = vv[ch] - mu;
    float var = wsum64(dv*dv) * (1.0f/(float)HD);
    float y = dv * rsqrtf(var + 1e-5f) * gam + bet;
    float ge = 0.5f * y * (1.0f + erff(y * 0.70710678118654752f));
    float o = ge + bf2f(pos[h*CDIM + c]);
    ht[((size_t)(b*NH + h))*CDIM + c] = f2bf(o);
  }
}

// ---------------------------------------------------------------- GEMM
// R15-proven: 128x128 tile, BK=32, 4 waves, ring-5 buffers (80KB), depth-3
// prefetch, single barrier/iter (WAR distance 2), counted vmcnt, XOR seg
// swizzle both sides, m204 XCD remap. MODE 0: contiguous qkvo write.
template<int MODE>
__global__ __launch_bounds__(256, 2) void gemm_kernel(
    const u16* __restrict__ A0c, const void* __restrict__ A0r,
    const u16* __restrict__ A1,
    const u16* __restrict__ Bt, const u16* __restrict__ bias,
    u16* __restrict__ qout,
    void* __restrict__ outv, float* __restrict__ csb, const int* __restrict__ flag)
{
  const int tid = threadIdx.x;
  const int lane = tid & 63;
  const int w = tid >> 6;
  const int wm = w >> 1, wn = w & 1;
  const int lr = lane & 15, kg = lane >> 4;

  const int NT = gridDim.x;
  const int nwg = NT * gridDim.y;
  const int orig = blockIdx.y * NT + blockIdx.x;
  const int xcd = orig & 7, sIdx = orig >> 3;
  const int q = nwg >> 3, r = nwg & 7;
  const int wg = ((xcd < r) ? xcd*(q+1) : r*(q+1) + (xcd-r)*q) + sIdx;
  const int tm = wg / NT, tn = wg - tm*NT;

  __shared__ __align__(16) u16 As[5][4096];   // [buf][row*32 + seg*8 + e]
  __shared__ __align__(16) u16 Bs[5][4096];

  const int f = *flag;
  const u16* A0 = (MODE == 0) ? (f ? (const u16*)A0r : A0c) : A0c;

  f32x4 acc[4][4];
  #pragma unroll
  for (int i=0;i<4;i++)
    #pragma unroll
    for (int j=0;j<4;j++) acc[i][j] = (f32x4){0.f,0.f,0.f,0.f};

  const u16* garow[2];
  const u16* gbrow[2];
  #pragma unroll
  for (int i=0;i<2;i++){
    int row = (i*4 + w)*16 + (lane >> 2);
    int rr = tm*128 + row; if (rr > GM-1) rr = GM-1;
    if (MODE == 0) {
      int bb = rr / TT; int t = rr - bb*TT;
      garow[i] = (t < NTOK) ? (A0 + (size_t)(bb*NTOK + t)*CDIM)
                            : (A1 + (size_t)(bb*NH + (t - NTOK))*CDIM);
    } else {
      garow[i] = A0 + (size_t)rr*CDIM;
    }
    gbrow[i] = Bt + (size_t)(tn*128 + row)*CDIM;
  }
  const int gseg = (lane & 3) ^ ((lane >> 3) & 3);   // = seg ^ ((row>>1)&3)

#define STAGE(kt_, bf_) do { \
    const int ko_ = (kt_)*32 + gseg*8; \
    gll16(garow[0] + ko_, (void*)&As[bf_][(0*4+w)*512]); \
    gll16(garow[1] + ko_, (void*)&As[bf_][(1*4+w)*512]); \
    gll16(gbrow[0] + ko_, (void*)&Bs[bf_][(0*4+w)*512]); \
    gll16(gbrow[1] + ko_, (void*)&Bs[bf_][(1*4+w)*512]); \
  } while(0)

  STAGE(0, 0);
  STAGE(1, 1);
  STAGE(2, 2);

  const int spA = kg ^ ((lr >> 1) & 3);   // read-side swizzled segment

  #pragma unroll
  for (int kt = 0; kt < 24; kt++) {
    const int cb = kt % 5;
    if (kt < 21) {
      STAGE(kt+3, (kt+3)%5);
      asm volatile("s_waitcnt vmcnt(12)" ::: "memory");   // stage kt drained
    } else if (kt == 21) {
      asm volatile("s_waitcnt vmcnt(8)" ::: "memory");
    } else if (kt == 22) {
      asm volatile("s_waitcnt vmcnt(4)" ::: "memory");
    } else {
      asm volatile("s_waitcnt vmcnt(0)" ::: "memory");
    }
    __builtin_amdgcn_s_barrier();     // single barrier/iter (ring-5 WAR proof)

    bf16x8 av[4], bv[4];
    #pragma unroll
    for (int mi=0; mi<4; mi++)
      av[mi] = *(const bf16x8*)&As[cb][(wm*64+mi*16+lr)*32 + spA*8];
    #pragma unroll
    for (int ni=0; ni<4; ni++)
      bv[ni] = *(const bf16x8*)&Bs[cb][(wn*64+ni*16+lr)*32 + spA*8];
    #pragma unroll
    for (int mi=0; mi<4; mi++)
      #pragma unroll
      for (int ni=0; ni<4; ni++)
        acc[mi][ni] = __builtin_amdgcn_mfma_f32_16x16x32_bf16(av[mi], bv[ni], acc[mi][ni], 0,0,0);
  }
#undef STAGE

  #pragma unroll
  for (int mi=0; mi<4; mi++){
    const int rb = tm*128 + wm*64 + mi*16 + kg*4;
    #pragma unroll
    for (int ni=0; ni<4; ni++){
      const int c = tn*128 + wn*64 + ni*16 + lr;
      const float bs = bf2f(bias[c]);
      if (MODE == 0) {
        #pragma unroll
        for (int j=0;j<4;j++){
          int rr = rb + j;
          if (rr < GM) qout[(size_t)rr*NQKV + c] = f2bf(acc[mi][ni][j] + bs);
        }
      } else {
        #pragma unroll
        for (int j=0;j<4;j++){
          int rr = rb + j;
          if (rr < GM) {
            int bb = rr / TT; int t = rr - bb*TT;
            float v = acc[mi][ni][j] + bs;
            if (t >= 1 && t < NTOK) {
              size_t oi = ((size_t)(bb*NTOK + t))*CDIM + c;
              if (f) ((u16*)outv)[oi] = f2bf(v);
              else   ((float*)outv)[oi] = v;
            } else {
              int idx = (t == 0) ? 0 : (t - NTOK + 1);   // 0, 1..12
              csb[((size_t)(bb*13 + idx))*CDIM + c] = v;
            }
          }
        }
      }
    }
  }
}

// ---------------------------------------------------------------- vtrans
__global__ __launch_bounds__(256) void vtrans_kernel(
    const u16* __restrict__ qkvo, u16* __restrict__ vb)
{
  __shared__ u16 lds[64][66];
  const int tt0 = blockIdx.x*64;
  const int bh = blockIdx.y;
  const int b = bh / NH, h = bh - b*NH;
  const int c = threadIdx.x & 63, r0 = threadIdx.x >> 6;
  #pragma unroll
  for (int i=0;i<16;i++) {
    int t = tt0 + i*4 + r0;
    u16 v = 0;
    if (t < TT) v = qkvo[(size_t)(b*TT + t)*NQKV + 1536 + h*64 + c];
    lds[i*4+r0][c] = v;
  }
  __syncthreads();
  #pragma unroll
  for (int i=0;i<16;i++) {
    int d = i*4 + r0;
    int t = tt0 + c;
    if (t < VTP) vb[((size_t)(bh)*HD + d)*VTP + t] = lds[c][d];
  }
}

// ---------------------------------------------------------------- attention
__global__ __launch_bounds__(256) void attn_kernel(
    const u16* __restrict__ qkvo, const u16* __restrict__ vt, u16* __restrict__ ob)
{
  __shared__ __align__(16) u16 P[4][7*16*32];   // 28672 B
  const int tid = threadIdx.x;
  const int lane = tid & 63;
  const int w = tid >> 6;
  const int lr = lane & 15, kg = lane >> 4;

  const int cid = blockIdx.x*4 + w;
  const int bh = cid / 14, ck = cid - bh*14;
  const int b = bh / NH, h = bh - b*NH;
  const int q0 = ck*16;

  const u16* qg  = qkvo + (size_t)(b*TT)*NQKV + h*64;
  const u16* kgp = qg + CDIM;
  const u16* vg  = vt + (size_t)bh*HD*VTP;

  int qrow = q0 + lr; if (qrow > TT-1) qrow = TT-1;
  const bf16x8 qf0 = *(const bf16x8*)&qg[(size_t)qrow*NQKV + kg*8];
  const bf16x8 qf1 = *(const bf16x8*)&qg[(size_t)qrow*NQKV + 32 + kg*8];

  f32x4 sv[14];
  #pragma unroll
  for (int kt = 0; kt < 14; kt++) {
    int krow = kt*16 + lr; if (krow > TT-1) krow = TT-1;
    const u16* kr = kgp + (size_t)krow*NQKV;
    bf16x8 kf0 = *(const bf16x8*)&kr[kg*8];
    bf16x8 kf1 = *(const bf16x8*)&kr[32 + kg*8];
    f32x4 sa = {0.f,0.f,0.f,0.f};
    sa = __builtin_amdgcn_mfma_f32_16x16x32_bf16(kf0, qf0, sa, 0,0,0);
    sa = __builtin_amdgcn_mfma_f32_16x16x32_bf16(kf1, qf1, sa, 0,0,0);
    sv[kt] = sa;
  }

  float m = -3.0e38f;
  #pragma unroll
  for (int kt = 0; kt < 13; kt++)
    #pragma unroll
    for (int j=0;j<4;j++){ sv[kt][j] *= 0.125f; m = fmaxf(m, sv[kt][j]); }
  #pragma unroll
  for (int j=0;j<4;j++){
    sv[13][j] *= 0.125f;
    if (208 + kg*4 + j < TT) m = fmaxf(m, sv[13][j]);
  }
  m = fmaxf(m, __shfl_xor(m, 16, 64));
  m = fmaxf(m, __shfl_xor(m, 32, 64));

  float ssum = 0.f;
  #pragma unroll
  for (int kt = 0; kt < 13; kt++)
    #pragma unroll
    for (int j=0;j<4;j++){ float e = __expf(sv[kt][j] - m); sv[kt][j] = e; ssum += e; }
  #pragma unroll
  for (int j=0;j<4;j++){
    float e = (208 + kg*4 + j < TT) ? __expf(sv[13][j] - m) : 0.f;
    sv[13][j] = e; ssum += e;
  }
  ssum += __shfl_xor(ssum, 16, 64);
  ssum += __shfl_xor(ssum, 32, 64);
  const float inv = 1.0f / ssum;

  u16* Pw = &P[w][0];
  #pragma unroll
  for (int kt = 0; kt < 14; kt++) {
    u16x4 pk;
    #pragma unroll
    for (int j=0;j<4;j++) pk[j] = f2bf(sv[kt][j] * inv);
    *(u16x4*)&Pw[(kt>>1)*512 + lr*32 + (kt&1)*16 + kg*4] = pk;
  }

  f32x4 acc[4];
  #pragma unroll
  for (int dt=0; dt<4; dt++) acc[dt] = (f32x4){0.f,0.f,0.f,0.f};
  #pragma unroll
  for (int ks = 0; ks < 7; ks++) {
    bf16x8 pf = *(const bf16x8*)&Pw[ks*512 + lr*32 + kg*8];
    #pragma unroll
    for (int dt = 0; dt < 4; dt++) {
      bf16x8 vf = *(const bf16x8*)&vg[(dt*16+lr)*VTP + ks*32 + kg*8];
      acc[dt] = __builtin_amdgcn_mfma_f32_16x16x32_bf16(pf, vf, acc[dt], 0,0,0);
    }
  }

  #pragma unroll
  for (int dt = 0; dt < 4; dt++)
    #pragma unroll
    for (int j = 0; j < 4; j++) {
      int tq = q0 + kg*4 + j;
      if (tq < TT)
        ob[((size_t)(b*TT + tq))*CDIM + h*HD + dt*16 + lr] = f2bf(acc[dt][j]);
    }
}

// ---------------------------------------------------------------- final2 (cls row)
__global__ __launch_bounds__(256) void final2_kernel(
    const float* __restrict__ csb, void* __restrict__ outv, const int* __restrict__ flag)
{
  const int f = *flag;
  int i = blockIdx.x*256 + threadIdx.x;
  if (i >= BATCH*CDIM) return;
  int b = i / CDIM, c = i - b*CDIM;
  const float* p = csb + (size_t)b*13*CDIM + c;
  float s = 0.f;
  #pragma unroll
  for (int j = 1; j <= 12; j++) s += p[(size_t)j*CDIM];
  float v = p[0] + s * (1.0f/12.0f);
  size_t oi = ((size_t)b*NTOK)*CDIM + c;
  if (f) ((u16*)outv)[oi] = f2bf(v);
  else   ((float*)outv)[oi] = v;
}

// ---------------------------------------------------------------- launch
extern "C" void kernel_launch(void* const* d_in, const int* in_sizes, int n_in,
                              void* d_out, int out_size, void* d_ws, size_t ws_size,
                              hipStream_t stream)
{
  char* ws = (char*)d_ws;
  size_t off = 0;
  auto alloc = [&](size_t bytes)->void* {
    void* p = ws + off; off += (bytes + 255) & ~(size_t)255; return p;
  };

  int* flag = (int*)alloc(256);

  u16* cin[10];
  for (int i = 0; i < 10; i++) cin[i] = (u16*)alloc((size_t)in_sizes[i]*2);

  u16* qkvT  = (u16*)alloc((size_t)3*CDIM*CDIM*2);        // 2304 x 768
  u16* projT = (u16*)alloc((size_t)CDIM*CDIM*2);          // 768 x 768
  u16* htb_  = (u16*)alloc((size_t)BATCH*NH*CDIM*2);      // (B*H) x 768
  float* mbuf = (float*)alloc((size_t)BATCH*CDIM*4);      // per-batch col means
  u16* qkvo  = (u16*)alloc((size_t)GM*NQKV*2);            // (B*T) x 2304
  u16* vb    = (u16*)alloc((size_t)BATCH*NH*HD*VTP*2);    // (B,H,HD,VTP)
  float* csb = (float*)alloc((size_t)BATCH*13*CDIM*4);    // cls side buffer
  u16* ao    = cin[0];   // alias: x dead after gemm<0>; cin[1] never used

  detect_kernel<<<1, 64, 0, stream>>>((const u16*)d_in[0], flag);

  CA ca;
  for (int i = 0; i < 10; i++) { ca.in[i] = d_in[i]; ca.out[i] = cin[i]; ca.n[i] = in_sizes[i]; }
  convert_all_kernel<<<dim3(64, 10), 256, 0, stream>>>(ca, flag);

  transpose2_kernel<<<576, 256, 0, stream>>>(d_in[1], d_in[3], qkvT, projT, flag);
  mean_kernel<<<dim3(BATCH, 3), 256, 0, stream>>>(cin[0], d_in[0], mbuf, flag);
  htmm_kernel<<<dim3(BATCH, NH), 256, 0, stream>>>(mbuf, cin[5], cin[6], cin[7], cin[8], cin[9], htb_);
  gemm_kernel<0><<<dim3(NQKV/128, (GM+127)/128), 256, 0, stream>>>(
      cin[0], d_in[0], htb_, qkvT, cin[2], qkvo, nullptr, nullptr, flag);
  vtrans_kernel<<<dim3(4, BATCH*NH), 256, 0, stream>>>(qkvo, vb);
  attn_kernel<<<(BATCH*NH*14)/4, 256, 0, stream>>>(qkvo, vb, ao);
  gemm_kernel<1><<<dim3(CDIM/128, (GM+127)/128), 256, 0, stream>>>(
      ao, nullptr, nullptr, projT, cin[4], nullptr, d_out, csb, flag);
  final2_kernel<<<(BATCH*CDIM+255)/256, 256, 0, stream>>>(csb, d_out, flag);
}

// Round 17
// 245.926 us; speedup vs baseline: 1.1210x; 1.1210x over previous
//
#include <hip/hip_runtime.h>
#include <cstdint>
#include <cstddef>

typedef unsigned short u16;
typedef __attribute__((ext_vector_type(8))) __bf16 bf16x8;
typedef __attribute__((ext_vector_type(4))) unsigned short u16x4;
typedef __attribute__((ext_vector_type(8))) unsigned short u16x8;
typedef __attribute__((ext_vector_type(4))) float f32x4;

#define NTOK 197
#define TT   209
#define CDIM 768
#define NH   12
#define HD   64
#define BATCH 64
#define GM (BATCH*TT)   // 13376
#define VTP 224         // padded T stride for transposed V
#define NQKV 2304

__device__ __forceinline__ float bf2f(u16 u){ return __uint_as_float(((unsigned)u)<<16); }
__device__ __forceinline__ u16 f2bf(float f){
  unsigned x = __float_as_uint(f);
  return (u16)((x + 0x7FFFu + ((x>>16)&1u)) >> 16);   // RNE; inputs finite
}

__device__ __forceinline__ void gll16(const void* g, void* l){
  __builtin_amdgcn_global_load_lds((const __attribute__((address_space(1))) void*)g,
                                   (__attribute__((address_space(3))) void*)l,
                                   16, 0, 0);
}

__device__ __forceinline__ float wsum64(float v){
  #pragma unroll
  for (int o = 32; o > 0; o >>= 1) v += __shfl_xor(v, o, 64);
  return v;
}

// ---------------------------------------------------------------- dtype detect
__global__ __launch_bounds__(64) void detect_kernel(const u16* __restrict__ x, int* flag){
  const int lane = threadIdx.x;
  float mx = 0.f;
  #pragma unroll
  for (int i = 0; i < 16; i++) {
    float v = fabsf(bf2f(x[i*64 + lane]));
    if (!(v < 1e30f)) v = 1e30f;
    mx = fmaxf(mx, v);
  }
  #pragma unroll
  for (int o = 32; o; o >>= 1) mx = fmaxf(mx, __shfl_xor(mx, o, 64));
  if (lane == 0) *flag = (mx < 1e5f) ? 1 : 0;   // 1 = device buffers are bf16
}

// ---------------------------------------------------------------- fused convert
struct CA { const void* in[10]; void* out[10]; int n[10]; };
__global__ __launch_bounds__(256) void convert_all_kernel(CA a, const int* __restrict__ flag){
  const int seg = blockIdx.y;
  if (seg == 1 || seg == 3) return;
  const int f = *flag;
  if (seg == 0 && f) return;
  const int n = a.n[seg];
  const int n4 = n >> 2;
  u16* out = (u16*)a.out[seg];
  if (f) {
    const u16x4* in = (const u16x4*)a.in[seg];
    for (int i = blockIdx.x*256 + threadIdx.x; i < n4; i += gridDim.x*256)
      ((u16x4*)out)[i] = in[i];
  } else {
    const f32x4* in = (const f32x4*)a.in[seg];
    for (int i = blockIdx.x*256 + threadIdx.x; i < n4; i += gridDim.x*256){
      f32x4 v = in[i];
      u16x4 o;
      #pragma unroll
      for (int j=0;j<4;j++) o[j] = f2bf(v[j]);
      ((u16x4*)out)[i] = o;
    }
  }
  if (blockIdx.x == 0 && (int)threadIdx.x < (n & 3)) {
    int i = (n4 << 2) + threadIdx.x;
    out[i] = f ? ((const u16*)a.in[seg])[i] : f2bf(((const float*)a.in[seg])[i]);
  }
}

// ---------------------------------------------------------------- fused transpose (+convert)
__global__ __launch_bounds__(256) void transpose2_kernel(
    const void* __restrict__ w1, const void* __restrict__ w2,
    u16* __restrict__ o1, u16* __restrict__ o2, const int* __restrict__ flag)
{
  __shared__ u16 lds[64][66];
  const int f = *flag;
  int bid = blockIdx.x;
  const void* in; u16* out; int K, N, tx, ty;
  if (bid < 432) { in = w1; out = o1; K = CDIM; N = NQKV; tx = bid % 36; ty = bid / 36; }
  else { bid -= 432; in = w2; out = o2; K = CDIM; N = CDIM; tx = bid % 12; ty = bid / 12; }
  const int n0 = tx*64, k0 = ty*64;
  const int c = threadIdx.x & 63, r0 = threadIdx.x >> 6;
  #pragma unroll
  for (int i=0;i<16;i++) {
    int r = i*4 + r0;
    size_t idx = (size_t)(k0+r)*N + n0 + c;
    lds[r][c] = f ? ((const u16*)in)[idx] : f2bf(((const float*)in)[idx]);
  }
  __syncthreads();
  #pragma unroll
  for (int i=0;i<16;i++) {
    int r = i*4 + r0;
    out[(size_t)(n0+r)*K + k0 + c] = lds[c][r];
  }
}

// ---------------------------------------------------------------- mean (ht phase 1)
__global__ __launch_bounds__(256) void mean_kernel(
    const u16* __restrict__ xc, const void* __restrict__ xr,
    float* __restrict__ mbuf, const int* __restrict__ flag)
{
  const int b = blockIdx.x, s = blockIdx.y;
  const int tid = threadIdx.x;
  const int f = *flag;
  const u16* x = f ? (const u16*)xr : xc;
  const u16* xp = x + (size_t)b*NTOK*CDIM + s*256 + tid;
  float cs = 0.f;
  for (int n = 0; n < NTOK; n++) cs += bf2f(xp[(size_t)n*CDIM]);
  mbuf[(size_t)b*CDIM + s*256 + tid] = cs * (1.0f/(float)NTOK);
}

// ---------------------------------------------------------------- ht matvec+LN (phase 2)
__global__ __launch_bounds__(256) void htmm_kernel(
    const float* __restrict__ mbuf,
    const u16* __restrict__ htw, const u16* __restrict__ htb,
    const u16* __restrict__ lng, const u16* __restrict__ lnb,
    const u16* __restrict__ pos, u16* __restrict__ ht)
{
  const int b = blockIdx.x, h = blockIdx.y;
  const int tid = threadIdx.x;
  __shared__ float msh[64];
  if (tid < 64) msh[tid] = mbuf[(size_t)b*CDIM + h*HD + tid];
  __syncthreads();

  float v0 = bf2f(htb[tid]), v1 = bf2f(htb[tid+256]), v2 = bf2f(htb[tid+512]);
  for (int d = 0; d < HD; d++) {
    const float md = msh[d];
    const u16* wr = htw + (size_t)d*CDIM;
    v0 += md * bf2f(wr[tid]);
    v1 += md * bf2f(wr[tid+256]);
    v2 += md * bf2f(wr[tid+512]);
  }
  const float gam = bf2f(lng[tid & 63]), bet = bf2f(lnb[tid & 63]);
  float vv[3] = {v0, v1, v2};
  #pragma unroll
  for (int ch = 0; ch < 3; ch++) {
    int c = ch*256 + tid;
    float mu = wsum64(vv[ch]) * (1.0f/(float)HD);
    float dv = vv[ch] - mu;
    float var = wsum64(dv*dv) * (1.0f/(float)HD);
    float y = dv * rsqrtf(var + 1e-5f) * gam + bet;
    float ge = 0.5f * y * (1.0f + erff(y * 0.70710678118654752f));
    float o = ge + bf2f(pos[h*CDIM + c]);
    ht[((size_t)(b*NH + h))*CDIM + c] = f2bf(o);
  }
}

// ---------------------------------------------------------------- GEMM
// R15-proven: 128x128 tile, BK=32, 4 waves, ring-5 buffers (80KB), depth-3
// prefetch, single barrier/iter (WAR distance 2), counted vmcnt, XOR seg
// swizzle both sides, m204 XCD remap. MODE 0: contiguous qkvo write.
template<int MODE>
__global__ __launch_bounds__(256, 2) void gemm_kernel(
    const u16* __restrict__ A0c, const void* __restrict__ A0r,
    const u16* __restrict__ A1,
    const u16* __restrict__ Bt, const u16* __restrict__ bias,
    u16* __restrict__ qout,
    void* __restrict__ outv, float* __restrict__ csb, const int* __restrict__ flag)
{
  const int tid = threadIdx.x;
  const int lane = tid & 63;
  const int w = tid >> 6;
  const int wm = w >> 1, wn = w & 1;
  const int lr = lane & 15, kg = lane >> 4;

  const int NT = gridDim.x;
  const int nwg = NT * gridDim.y;
  const int orig = blockIdx.y * NT + blockIdx.x;
  const int xcd = orig & 7, sIdx = orig >> 3;
  const int q = nwg >> 3, r = nwg & 7;
  const int wg = ((xcd < r) ? xcd*(q+1) : r*(q+1) + (xcd-r)*q) + sIdx;
  const int tm = wg / NT, tn = wg - tm*NT;

  __shared__ __align__(16) u16 As[5][4096];   // [buf][row*32 + seg*8 + e]
  __shared__ __align__(16) u16 Bs[5][4096];

  const int f = *flag;
  const u16* A0 = (MODE == 0) ? (f ? (const u16*)A0r : A0c) : A0c;

  f32x4 acc[4][4];
  #pragma unroll
  for (int i=0;i<4;i++)
    #pragma unroll
    for (int j=0;j<4;j++) acc[i][j] = (f32x4){0.f,0.f,0.f,0.f};

  const u16* garow[2];
  const u16* gbrow[2];
  #pragma unroll
  for (int i=0;i<2;i++){
    int row = (i*4 + w)*16 + (lane >> 2);
    int rr = tm*128 + row; if (rr > GM-1) rr = GM-1;
    if (MODE == 0) {
      int bb = rr / TT; int t = rr - bb*TT;
      garow[i] = (t < NTOK) ? (A0 + (size_t)(bb*NTOK + t)*CDIM)
                            : (A1 + (size_t)(bb*NH + (t - NTOK))*CDIM);
    } else {
      garow[i] = A0 + (size_t)rr*CDIM;
    }
    gbrow[i] = Bt + (size_t)(tn*128 + row)*CDIM;
  }
  const int gseg = (lane & 3) ^ ((lane >> 3) & 3);   // = seg ^ ((row>>1)&3)

#define STAGE(kt_, bf_) do { \
    const int ko_ = (kt_)*32 + gseg*8; \
    gll16(garow[0] + ko_, (void*)&As[bf_][(0*4+w)*512]); \
    gll16(garow[1] + ko_, (void*)&As[bf_][(1*4+w)*512]); \
    gll16(gbrow[0] + ko_, (void*)&Bs[bf_][(0*4+w)*512]); \
    gll16(gbrow[1] + ko_, (void*)&Bs[bf_][(1*4+w)*512]); \
  } while(0)

  STAGE(0, 0);
  STAGE(1, 1);
  STAGE(2, 2);

  const int spA = kg ^ ((lr >> 1) & 3);   // read-side swizzled segment

  #pragma unroll
  for (int kt = 0; kt < 24; kt++) {
    const int cb = kt % 5;
    if (kt < 21) {
      STAGE(kt+3, (kt+3)%5);
      asm volatile("s_waitcnt vmcnt(12)" ::: "memory");   // stage kt drained
    } else if (kt == 21) {
      asm volatile("s_waitcnt vmcnt(8)" ::: "memory");
    } else if (kt == 22) {
      asm volatile("s_waitcnt vmcnt(4)" ::: "memory");
    } else {
      asm volatile("s_waitcnt vmcnt(0)" ::: "memory");
    }
    __builtin_amdgcn_s_barrier();     // single barrier/iter (ring-5 WAR proof)

    bf16x8 av[4], bv[4];
    #pragma unroll
    for (int mi=0; mi<4; mi++)
      av[mi] = *(const bf16x8*)&As[cb][(wm*64+mi*16+lr)*32 + spA*8];
    #pragma unroll
    for (int ni=0; ni<4; ni++)
      bv[ni] = *(const bf16x8*)&Bs[cb][(wn*64+ni*16+lr)*32 + spA*8];
    #pragma unroll
    for (int mi=0; mi<4; mi++)
      #pragma unroll
      for (int ni=0; ni<4; ni++)
        acc[mi][ni] = __builtin_amdgcn_mfma_f32_16x16x32_bf16(av[mi], bv[ni], acc[mi][ni], 0,0,0);
  }
#undef STAGE

  #pragma unroll
  for (int mi=0; mi<4; mi++){
    const int rb = tm*128 + wm*64 + mi*16 + kg*4;
    #pragma unroll
    for (int ni=0; ni<4; ni++){
      const int c = tn*128 + wn*64 + ni*16 + lr;
      const float bs = bf2f(bias[c]);
      if (MODE == 0) {
        #pragma unroll
        for (int j=0;j<4;j++){
          int rr = rb + j;
          if (rr < GM) qout[(size_t)rr*NQKV + c] = f2bf(acc[mi][ni][j] + bs);
        }
      } else {
        #pragma unroll
        for (int j=0;j<4;j++){
          int rr = rb + j;
          if (rr < GM) {
            int bb = rr / TT; int t = rr - bb*TT;
            float v = acc[mi][ni][j] + bs;
            if (t >= 1 && t < NTOK) {
              size_t oi = ((size_t)(bb*NTOK + t))*CDIM + c;
              if (f) ((u16*)outv)[oi] = f2bf(v);
              else   ((float*)outv)[oi] = v;
            } else {
              int idx = (t == 0) ? 0 : (t - NTOK + 1);   // 0, 1..12
              csb[((size_t)(bb*13 + idx))*CDIM + c] = v;
            }
          }
        }
      }
    }
  }
}

// ---------------------------------------------------------------- vtrans
__global__ __launch_bounds__(256) void vtrans_kernel(
    const u16* __restrict__ qkvo, u16* __restrict__ vb)
{
  __shared__ u16 lds[64][66];
  const int tt0 = blockIdx.x*64;
  const int bh = blockIdx.y;
  const int b = bh / NH, h = bh - b*NH;
  const int c = threadIdx.x & 63, r0 = threadIdx.x >> 6;
  #pragma unroll
  for (int i=0;i<16;i++) {
    int t = tt0 + i*4 + r0;
    u16 v = 0;
    if (t < TT) v = qkvo[(size_t)(b*TT + t)*NQKV + 1536 + h*64 + c];
    lds[i*4+r0][c] = v;
  }
  __syncthreads();
  #pragma unroll
  for (int i=0;i<16;i++) {
    int d = i*4 + r0;
    int t = tt0 + c;
    if (t < VTP) vb[((size_t)(bh)*HD + d)*VTP + t] = lds[c][d];
  }
}

// ---------------------------------------------------------------- attention
__global__ __launch_bounds__(256) void attn_kernel(
    const u16* __restrict__ qkvo, const u16* __restrict__ vt, u16* __restrict__ ob)
{
  __shared__ __align__(16) u16 P[4][7*16*32];   // 28672 B
  const int tid = threadIdx.x;
  const int lane = tid & 63;
  const int w = tid >> 6;
  const int lr = lane & 15, kg = lane >> 4;

  const int cid = blockIdx.x*4 + w;
  const int bh = cid / 14, ck = cid - bh*14;
  const int b = bh / NH, h = bh - b*NH;
  const int q0 = ck*16;

  const u16* qg  = qkvo + (size_t)(b*TT)*NQKV + h*64;
  const u16* kgp = qg + CDIM;
  const u16* vg  = vt + (size_t)bh*HD*VTP;

  int qrow = q0 + lr; if (qrow > TT-1) qrow = TT-1;
  const bf16x8 qf0 = *(const bf16x8*)&qg[(size_t)qrow*NQKV + kg*8];
  const bf16x8 qf1 = *(const bf16x8*)&qg[(size_t)qrow*NQKV + 32 + kg*8];

  f32x4 sv[14];
  #pragma unroll
  for (int kt = 0; kt < 14; kt++) {
    int krow = kt*16 + lr; if (krow > TT-1) krow = TT-1;
    const u16* kr = kgp + (size_t)krow*NQKV;
    bf16x8 kf0 = *(const bf16x8*)&kr[kg*8];
    bf16x8 kf1 = *(const bf16x8*)&kr[32 + kg*8];
    f32x4 sa = {0.f,0.f,0.f,0.f};
    sa = __builtin_amdgcn_mfma_f32_16x16x32_bf16(kf0, qf0, sa, 0,0,0);
    sa = __builtin_amdgcn_mfma_f32_16x16x32_bf16(kf1, qf1, sa, 0,0,0);
    sv[kt] = sa;
  }

  float m = -3.0e38f;
  #pragma unroll
  for (int kt = 0; kt < 13; kt++)
    #pragma unroll
    for (int j=0;j<4;j++){ sv[kt][j] *= 0.125f; m = fmaxf(m, sv[kt][j]); }
  #pragma unroll
  for (int j=0;j<4;j++){
    sv[13][j] *= 0.125f;
    if (208 + kg*4 + j < TT) m = fmaxf(m, sv[13][j]);
  }
  m = fmaxf(m, __shfl_xor(m, 16, 64));
  m = fmaxf(m, __shfl_xor(m, 32, 64));

  float ssum = 0.f;
  #pragma unroll
  for (int kt = 0; kt < 13; kt++)
    #pragma unroll
    for (int j=0;j<4;j++){ float e = __expf(sv[kt][j] - m); sv[kt][j] = e; ssum += e; }
  #pragma unroll
  for (int j=0;j<4;j++){
    float e = (208 + kg*4 + j < TT) ? __expf(sv[13][j] - m) : 0.f;
    sv[13][j] = e; ssum += e;
  }
  ssum += __shfl_xor(ssum, 16, 64);
  ssum += __shfl_xor(ssum, 32, 64);
  const float inv = 1.0f / ssum;

  u16* Pw = &P[w][0];
  #pragma unroll
  for (int kt = 0; kt < 14; kt++) {
    u16x4 pk;
    #pragma unroll
    for (int j=0;j<4;j++) pk[j] = f2bf(sv[kt][j] * inv);
    *(u16x4*)&Pw[(kt>>1)*512 + lr*32 + (kt&1)*16 + kg*4] = pk;
  }

  f32x4 acc[4];
  #pragma unroll
  for (int dt=0; dt<4; dt++) acc[dt] = (f32x4){0.f,0.f,0.f,0.f};
  #pragma unroll
  for (int ks = 0; ks < 7; ks++) {
    bf16x8 pf = *(const bf16x8*)&Pw[ks*512 + lr*32 + kg*8];
    #pragma unroll
    for (int dt = 0; dt < 4; dt++) {
      bf16x8 vf = *(const bf16x8*)&vg[(dt*16+lr)*VTP + ks*32 + kg*8];
      acc[dt] = __builtin_amdgcn_mfma_f32_16x16x32_bf16(pf, vf, acc[dt], 0,0,0);
    }
  }

  #pragma unroll
  for (int dt = 0; dt < 4; dt++)
    #pragma unroll
    for (int j = 0; j < 4; j++) {
      int tq = q0 + kg*4 + j;
      if (tq < TT)
        ob[((size_t)(b*TT + tq))*CDIM + h*HD + dt*16 + lr] = f2bf(acc[dt][j]);
    }
}

// ---------------------------------------------------------------- final2 (cls row)
__global__ __launch_bounds__(256) void final2_kernel(
    const float* __restrict__ csb, void* __restrict__ outv, const int* __restrict__ flag)
{
  const int f = *flag;
  int i = blockIdx.x*256 + threadIdx.x;
  if (i >= BATCH*CDIM) return;
  int b = i / CDIM, c = i - b*CDIM;
  const float* p = csb + (size_t)b*13*CDIM + c;
  float s = 0.f;
  #pragma unroll
  for (int j = 1; j <= 12; j++) s += p[(size_t)j*CDIM];
  float v = p[0] + s * (1.0f/12.0f);
  size_t oi = ((size_t)b*NTOK)*CDIM + c;
  if (f) ((u16*)outv)[oi] = f2bf(v);
  else   ((float*)outv)[oi] = v;
}

// ---------------------------------------------------------------- launch
extern "C" void kernel_launch(void* const* d_in, const int* in_sizes, int n_in,
                              void* d_out, int out_size, void* d_ws, size_t ws_size,
                              hipStream_t stream)
{
  char* ws = (char*)d_ws;
  size_t off = 0;
  auto alloc = [&](size_t bytes)->void* {
    void* p = ws + off; off += (bytes + 255) & ~(size_t)255; return p;
  };

  int* flag = (int*)alloc(256);

  u16* cin[10];
  for (int i = 0; i < 10; i++) cin[i] = (u16*)alloc((size_t)in_sizes[i]*2);

  u16* qkvT  = (u16*)alloc((size_t)3*CDIM*CDIM*2);        // 2304 x 768
  u16* projT = (u16*)alloc((size_t)CDIM*CDIM*2);          // 768 x 768
  u16* htb_  = (u16*)alloc((size_t)BATCH*NH*CDIM*2);      // (B*H) x 768
  float* mbuf = (float*)alloc((size_t)BATCH*CDIM*4);      // per-batch col means
  u16* qkvo  = (u16*)alloc((size_t)GM*NQKV*2);            // (B*T) x 2304
  u16* vb    = (u16*)alloc((size_t)BATCH*NH*HD*VTP*2);    // (B,H,HD,VTP)
  float* csb = (float*)alloc((size_t)BATCH*13*CDIM*4);    // cls side buffer
  u16* ao    = cin[0];   // alias: x dead after gemm<0>; cin[1] never used

  detect_kernel<<<1, 64, 0, stream>>>((const u16*)d_in[0], flag);

  CA ca;
  for (int i = 0; i < 10; i++) { ca.in[i] = d_in[i]; ca.out[i] = cin[i]; ca.n[i] = in_sizes[i]; }
  convert_all_kernel<<<dim3(256, 10), 256, 0, stream>>>(ca, flag);

  transpose2_kernel<<<576, 256, 0, stream>>>(d_in[1], d_in[3], qkvT, projT, flag);
  mean_kernel<<<dim3(BATCH, 3), 256, 0, stream>>>(cin[0], d_in[0], mbuf, flag);
  htmm_kernel<<<dim3(BATCH, NH), 256, 0, stream>>>(mbuf, cin[5], cin[6], cin[7], cin[8], cin[9], htb_);
  gemm_kernel<0><<<dim3(NQKV/128, (GM+127)/128), 256, 0, stream>>>(
      cin[0], d_in[0], htb_, qkvT, cin[2], qkvo, nullptr, nullptr, flag);
  vtrans_kernel<<<dim3(4, BATCH*NH), 256, 0, stream>>>(qkvo, vb);
  attn_kernel<<<(BATCH*NH*14)/4, 256, 0, stream>>>(qkvo, vb, ao);
  gemm_kernel<1><<<dim3(CDIM/128, (GM+127)/128), 256, 0, stream>>>(
      ao, nullptr, nullptr, projT, cin[4], nullptr, d_out, csb, flag);
  final2_kernel<<<(BATCH*CDIM+255)/256, 256, 0, stream>>>(csb, d_out, flag);
}

// Round 18
// 244.142 us; speedup vs baseline: 1.1292x; 1.0073x over previous
//
#include <hip/hip_runtime.h>
#include <cstdint>
#include <cstddef>

typedef unsigned short u16;
typedef __attribute__((ext_vector_type(8))) __bf16 bf16x8;
typedef __attribute__((ext_vector_type(4))) unsigned short u16x4;
typedef __attribute__((ext_vector_type(8))) unsigned short u16x8;
typedef __attribute__((ext_vector_type(4))) float f32x4;

#define NTOK 197
#define TT   209
#define CDIM 768
#define NH   12
#define HD   64
#define BATCH 64
#define GM (BATCH*TT)   // 13376
#define VTP 224         // padded T stride for transposed V
#define NQKV 2304

__device__ __forceinline__ float bf2f(u16 u){ return __uint_as_float(((unsigned)u)<<16); }
__device__ __forceinline__ u16 f2bf(float f){
  unsigned x = __float_as_uint(f);
  return (u16)((x + 0x7FFFu + ((x>>16)&1u)) >> 16);   // RNE; inputs finite
}

__device__ __forceinline__ void gll16(const void* g, void* l){
  __builtin_amdgcn_global_load_lds((const __attribute__((address_space(1))) void*)g,
                                   (__attribute__((address_space(3))) void*)l,
                                   16, 0, 0);
}

__device__ __forceinline__ float wsum64(float v){
  #pragma unroll
  for (int o = 32; o > 0; o >>= 1) v += __shfl_xor(v, o, 64);
  return v;
}

// ---------------------------------------------------------------- dtype detect
__global__ __launch_bounds__(64) void detect_kernel(const u16* __restrict__ x, int* flag){
  const int lane = threadIdx.x;
  float mx = 0.f;
  #pragma unroll
  for (int i = 0; i < 16; i++) {
    float v = fabsf(bf2f(x[i*64 + lane]));
    if (!(v < 1e30f)) v = 1e30f;
    mx = fmaxf(mx, v);
  }
  #pragma unroll
  for (int o = 32; o; o >>= 1) mx = fmaxf(mx, __shfl_xor(mx, o, 64));
  if (lane == 0) *flag = (mx < 1e5f) ? 1 : 0;   // 1 = device buffers are bf16
}

// ---------------------------------------------------------------- fused convert
// seg 1 repurposed: zero-fill vb pad rows (t in [TT,VTP)); seg 3 idle.
struct CA { const void* in[10]; void* out[10]; int n[10]; };
__global__ __launch_bounds__(256) void convert_all_kernel(CA a, const int* __restrict__ flag){
  const int seg = blockIdx.y;
  if (seg == 1) {
    int row = blockIdx.x*256 + threadIdx.x;
    if (row < a.n[1]) {
      u16* p = (u16*)a.out[1] + (size_t)row*VTP + TT;
      #pragma unroll
      for (int j = 0; j < VTP-TT; j++) p[j] = 0;
    }
    return;
  }
  if (seg == 3) return;
  const int f = *flag;
  if (seg == 0 && f) return;
  const int n = a.n[seg];
  const int n4 = n >> 2;
  u16* out = (u16*)a.out[seg];
  if (f) {
    const u16x4* in = (const u16x4*)a.in[seg];
    for (int i = blockIdx.x*256 + threadIdx.x; i < n4; i += gridDim.x*256)
      ((u16x4*)out)[i] = in[i];
  } else {
    const f32x4* in = (const f32x4*)a.in[seg];
    for (int i = blockIdx.x*256 + threadIdx.x; i < n4; i += gridDim.x*256){
      f32x4 v = in[i];
      u16x4 o;
      #pragma unroll
      for (int j=0;j<4;j++) o[j] = f2bf(v[j]);
      ((u16x4*)out)[i] = o;
    }
  }
  if (blockIdx.x == 0 && (int)threadIdx.x < (n & 3)) {
    int i = (n4 << 2) + threadIdx.x;
    out[i] = f ? ((const u16*)a.in[seg])[i] : f2bf(((const float*)a.in[seg])[i]);
  }
}

// ---------------------------------------------------------------- fused transpose (+convert)
__global__ __launch_bounds__(256) void transpose2_kernel(
    const void* __restrict__ w1, const void* __restrict__ w2,
    u16* __restrict__ o1, u16* __restrict__ o2, const int* __restrict__ flag)
{
  __shared__ u16 lds[64][66];
  const int f = *flag;
  int bid = blockIdx.x;
  const void* in; u16* out; int K, N, tx, ty;
  if (bid < 432) { in = w1; out = o1; K = CDIM; N = NQKV; tx = bid % 36; ty = bid / 36; }
  else { bid -= 432; in = w2; out = o2; K = CDIM; N = CDIM; tx = bid % 12; ty = bid / 12; }
  const int n0 = tx*64, k0 = ty*64;
  const int c = threadIdx.x & 63, r0 = threadIdx.x >> 6;
  #pragma unroll
  for (int i=0;i<16;i++) {
    int r = i*4 + r0;
    size_t idx = (size_t)(k0+r)*N + n0 + c;
    lds[r][c] = f ? ((const u16*)in)[idx] : f2bf(((const float*)in)[idx]);
  }
  __syncthreads();
  #pragma unroll
  for (int i=0;i<16;i++) {
    int r = i*4 + r0;
    out[(size_t)(n0+r)*K + k0 + c] = lds[c][r];
  }
}

// ---------------------------------------------------------------- mean (ht phase 1)
__global__ __launch_bounds__(256) void mean_kernel(
    const u16* __restrict__ xc, const void* __restrict__ xr,
    float* __restrict__ mbuf, const int* __restrict__ flag)
{
  const int b = blockIdx.x, s = blockIdx.y;
  const int tid = threadIdx.x;
  const int f = *flag;
  const u16* x = f ? (const u16*)xr : xc;
  const u16* xp = x + (size_t)b*NTOK*CDIM + s*256 + tid;
  float cs = 0.f;
  for (int n = 0; n < NTOK; n++) cs += bf2f(xp[(size_t)n*CDIM]);
  mbuf[(size_t)b*CDIM + s*256 + tid] = cs * (1.0f/(float)NTOK);
}

// ---------------------------------------------------------------- ht matvec+LN (phase 2)
__global__ __launch_bounds__(256) void htmm_kernel(
    const float* __restrict__ mbuf,
    const u16* __restrict__ htw, const u16* __restrict__ htb,
    const u16* __restrict__ lng, const u16* __restrict__ lnb,
    const u16* __restrict__ pos, u16* __restrict__ ht)
{
  const int b = blockIdx.x, h = blockIdx.y;
  const int tid = threadIdx.x;
  __shared__ float msh[64];
  if (tid < 64) msh[tid] = mbuf[(size_t)b*CDIM + h*HD + tid];
  __syncthreads();

  float v0 = bf2f(htb[tid]), v1 = bf2f(htb[tid+256]), v2 = bf2f(htb[tid+512]);
  for (int d = 0; d < HD; d++) {
    const float md = msh[d];
    const u16* wr = htw + (size_t)d*CDIM;
    v0 += md * bf2f(wr[tid]);
    v1 += md * bf2f(wr[tid+256]);
    v2 += md * bf2f(wr[tid+512]);
  }
  const float gam = bf2f(lng[tid & 63]), bet = bf2f(lnb[tid & 63]);
  float vv[3] = {v0, v1, v2};
  #pragma unroll
  for (int ch = 0; ch < 3; ch++) {
    int c = ch*256 + tid;
    float mu = wsum64(vv[ch]) * (1.0f/(float)HD);
    float dv = vv[ch] - mu;
    float var = wsum64(dv*dv) * (1.0f/(float)HD);
    float y = dv * rsqrtf(var + 1e-5f) * gam + bet;
    float ge = 0.5f * y * (1.0f + erff(y * 0.70710678118654752f));
    float o = ge + bf2f(pos[h*CDIM + c]);
    ht[((size_t)(b*NH + h))*CDIM + c] = f2bf(o);
  }
}

// ---------------------------------------------------------------- GEMM
// R15-proven: 128x128 tile, BK=32, 4 waves, ring-5 buffers (80KB), depth-3
// prefetch, single barrier/iter, counted vmcnt, XOR seg swizzle, m204 remap.
// MODE 0: q/k contiguous into qkvo; v written TRANSPOSED into vbo (B,H,HD,VTP).
template<int MODE>
__global__ __launch_bounds__(256, 2) void gemm_kernel(
    const u16* __restrict__ A0c, const void* __restrict__ A0r,
    const u16* __restrict__ A1,
    const u16* __restrict__ Bt, const u16* __restrict__ bias,
    u16* __restrict__ qout, u16* __restrict__ vbo,
    void* __restrict__ outv, float* __restrict__ csb, const int* __restrict__ flag)
{
  const int tid = threadIdx.x;
  const int lane = tid & 63;
  const int w = tid >> 6;
  const int wm = w >> 1, wn = w & 1;
  const int lr = lane & 15, kg = lane >> 4;

  const int NT = gridDim.x;
  const int nwg = NT * gridDim.y;
  const int orig = blockIdx.y * NT + blockIdx.x;
  const int xcd = orig & 7, sIdx = orig >> 3;
  const int q = nwg >> 3, r = nwg & 7;
  const int wg = ((xcd < r) ? xcd*(q+1) : r*(q+1) + (xcd-r)*q) + sIdx;
  const int tm = wg / NT, tn = wg - tm*NT;

  __shared__ __align__(16) u16 As[5][4096];   // [buf][row*32 + seg*8 + e]
  __shared__ __align__(16) u16 Bs[5][4096];

  const int f = *flag;
  const u16* A0 = (MODE == 0) ? (f ? (const u16*)A0r : A0c) : A0c;

  f32x4 acc[4][4];
  #pragma unroll
  for (int i=0;i<4;i++)
    #pragma unroll
    for (int j=0;j<4;j++) acc[i][j] = (f32x4){0.f,0.f,0.f,0.f};

  const u16* garow[2];
  const u16* gbrow[2];
  #pragma unroll
  for (int i=0;i<2;i++){
    int row = (i*4 + w)*16 + (lane >> 2);
    int rr = tm*128 + row; if (rr > GM-1) rr = GM-1;
    if (MODE == 0) {
      int bb = rr / TT; int t = rr - bb*TT;
      garow[i] = (t < NTOK) ? (A0 + (size_t)(bb*NTOK + t)*CDIM)
                            : (A1 + (size_t)(bb*NH + (t - NTOK))*CDIM);
    } else {
      garow[i] = A0 + (size_t)rr*CDIM;
    }
    gbrow[i] = Bt + (size_t)(tn*128 + row)*CDIM;
  }
  const int gseg = (lane & 3) ^ ((lane >> 3) & 3);   // = seg ^ ((row>>1)&3)

#define STAGE(kt_, bf_) do { \
    const int ko_ = (kt_)*32 + gseg*8; \
    gll16(garow[0] + ko_, (void*)&As[bf_][(0*4+w)*512]); \
    gll16(garow[1] + ko_, (void*)&As[bf_][(1*4+w)*512]); \
    gll16(gbrow[0] + ko_, (void*)&Bs[bf_][(0*4+w)*512]); \
    gll16(gbrow[1] + ko_, (void*)&Bs[bf_][(1*4+w)*512]); \
  } while(0)

  STAGE(0, 0);
  STAGE(1, 1);
  STAGE(2, 2);

  const int spA = kg ^ ((lr >> 1) & 3);   // read-side swizzled segment

  #pragma unroll
  for (int kt = 0; kt < 24; kt++) {
    const int cb = kt % 5;
    if (kt < 21) {
      STAGE(kt+3, (kt+3)%5);
      asm volatile("s_waitcnt vmcnt(12)" ::: "memory");   // stage kt drained
    } else if (kt == 21) {
      asm volatile("s_waitcnt vmcnt(8)" ::: "memory");
    } else if (kt == 22) {
      asm volatile("s_waitcnt vmcnt(4)" ::: "memory");
    } else {
      asm volatile("s_waitcnt vmcnt(0)" ::: "memory");
    }
    __builtin_amdgcn_s_barrier();     // single barrier/iter (ring-5 WAR proof)

    bf16x8 av[4], bv[4];
    #pragma unroll
    for (int mi=0; mi<4; mi++)
      av[mi] = *(const bf16x8*)&As[cb][(wm*64+mi*16+lr)*32 + spA*8];
    #pragma unroll
    for (int ni=0; ni<4; ni++)
      bv[ni] = *(const bf16x8*)&Bs[cb][(wn*64+ni*16+lr)*32 + spA*8];
    #pragma unroll
    for (int mi=0; mi<4; mi++)
      #pragma unroll
      for (int ni=0; ni<4; ni++)
        acc[mi][ni] = __builtin_amdgcn_mfma_f32_16x16x32_bf16(av[mi], bv[ni], acc[mi][ni], 0,0,0);
  }
#undef STAGE

  #pragma unroll
  for (int mi=0; mi<4; mi++){
    const int rb = tm*128 + wm*64 + mi*16 + kg*4;
    #pragma unroll
    for (int ni=0; ni<4; ni++){
      const int c = tn*128 + wn*64 + ni*16 + lr;
      const float bs = bf2f(bias[c]);
      if (MODE == 0) {
        if (c < 2*CDIM) {
          #pragma unroll
          for (int j=0;j<4;j++){
            int rr = rb + j;
            if (rr < GM) qout[(size_t)rr*NQKV + c] = f2bf(acc[mi][ni][j] + bs);
          }
        } else {
          const int hh = (c - 2*CDIM) >> 6;
          const int dd = c & 63;
          #pragma unroll
          for (int j=0;j<4;j++){
            int rr = rb + j;
            if (rr < GM) {
              int bb = rr / TT; int t = rr - bb*TT;
              vbo[((size_t)(bb*NH + hh)*HD + dd)*VTP + t] = f2bf(acc[mi][ni][j] + bs);
            }
          }
        }
      } else {
        #pragma unroll
        for (int j=0;j<4;j++){
          int rr = rb + j;
          if (rr < GM) {
            int bb = rr / TT; int t = rr - bb*TT;
            float v = acc[mi][ni][j] + bs;
            if (t >= 1 && t < NTOK) {
              size_t oi = ((size_t)(bb*NTOK + t))*CDIM + c;
              if (f) ((u16*)outv)[oi] = f2bf(v);
              else   ((float*)outv)[oi] = v;
            } else {
              int idx = (t == 0) ? 0 : (t - NTOK + 1);   // 0, 1..12
              csb[((size_t)(bb*13 + idx))*CDIM + c] = v;
            }
          }
        }
      }
    }
  }
}

// ---------------------------------------------------------------- attention v2
// One block (4 waves) per (b,h). K staged once into LDS [224][72] (zero-pad,
// 2-way-free bank pattern), one __syncthreads, then each wave independently
// processes q-chunks ck = w, w+4, ... with in-register softmax (swapped QK^T),
// per-wave P LDS, PV from transposed-V global. No further barriers.
__global__ __launch_bounds__(256) void attn_kernel(
    const u16* __restrict__ qkvo, const u16* __restrict__ vt, u16* __restrict__ ob)
{
  __shared__ __align__(16) u16 Kl[224*72];      // 32256 B
  __shared__ __align__(16) u16 P[4][7*16*32];   // 28672 B
  const int tid = threadIdx.x;
  const int lane = tid & 63;
  const int w = tid >> 6;
  const int lr = lane & 15, kg = lane >> 4;

  const int bh = blockIdx.x;
  const int b = bh / NH, h = bh - b*NH;

  const u16* qg  = qkvo + (size_t)(b*TT)*NQKV + h*64;
  const u16* kgp = qg + CDIM;
  const u16* vg  = vt + (size_t)bh*HD*VTP;

  for (int s = tid; s < 224*8; s += 256) {
    int kc = s >> 3, seg = s & 7;
    uint4 val = make_uint4(0,0,0,0);
    if (kc < TT) val = *(const uint4*)&kgp[(size_t)kc*NQKV + seg*8];
    *(uint4*)&Kl[kc*72 + seg*8] = val;
  }
  __syncthreads();

  u16* Pw = &P[w][0];
  for (int ck = w; ck < 14; ck += 4) {
    const int q0 = ck*16;
    int qrow = q0 + lr; if (qrow > TT-1) qrow = TT-1;
    const bf16x8 qf0 = *(const bf16x8*)&qg[(size_t)qrow*NQKV + kg*8];
    const bf16x8 qf1 = *(const bf16x8*)&qg[(size_t)qrow*NQKV + 32 + kg*8];

    f32x4 sv[14];
    #pragma unroll
    for (int kt = 0; kt < 14; kt++) {
      bf16x8 kf0 = *(const bf16x8*)&Kl[(kt*16+lr)*72 + kg*8];
      bf16x8 kf1 = *(const bf16x8*)&Kl[(kt*16+lr)*72 + 32 + kg*8];
      f32x4 sa = {0.f,0.f,0.f,0.f};
      sa = __builtin_amdgcn_mfma_f32_16x16x32_bf16(kf0, qf0, sa, 0,0,0);
      sa = __builtin_amdgcn_mfma_f32_16x16x32_bf16(kf1, qf1, sa, 0,0,0);
      sv[kt] = sa;
    }

    float m = -3.0e38f;
    #pragma unroll
    for (int kt = 0; kt < 13; kt++)
      #pragma unroll
      for (int j=0;j<4;j++){ sv[kt][j] *= 0.125f; m = fmaxf(m, sv[kt][j]); }
    #pragma unroll
    for (int j=0;j<4;j++){
      sv[13][j] *= 0.125f;
      if (208 + kg*4 + j < TT) m = fmaxf(m, sv[13][j]);
    }
    m = fmaxf(m, __shfl_xor(m, 16, 64));
    m = fmaxf(m, __shfl_xor(m, 32, 64));

    float ssum = 0.f;
    #pragma unroll
    for (int kt = 0; kt < 13; kt++)
      #pragma unroll
      for (int j=0;j<4;j++){ float e = __expf(sv[kt][j] - m); sv[kt][j] = e; ssum += e; }
    #pragma unroll
    for (int j=0;j<4;j++){
      float e = (208 + kg*4 + j < TT) ? __expf(sv[13][j] - m) : 0.f;
      sv[13][j] = e; ssum += e;
    }
    ssum += __shfl_xor(ssum, 16, 64);
    ssum += __shfl_xor(ssum, 32, 64);
    const float inv = 1.0f / ssum;

    #pragma unroll
    for (int kt = 0; kt < 14; kt++) {
      u16x4 pk;
      #pragma unroll
      for (int j=0;j<4;j++) pk[j] = f2bf(sv[kt][j] * inv);
      *(u16x4*)&Pw[(kt>>1)*512 + lr*32 + (kt&1)*16 + kg*4] = pk;
    }

    f32x4 acc[4];
    #pragma unroll
    for (int dt=0; dt<4; dt++) acc[dt] = (f32x4){0.f,0.f,0.f,0.f};
    #pragma unroll
    for (int ks = 0; ks < 7; ks++) {
      bf16x8 pf = *(const bf16x8*)&Pw[ks*512 + lr*32 + kg*8];
      #pragma unroll
      for (int dt = 0; dt < 4; dt++) {
        bf16x8 vf = *(const bf16x8*)&vg[(dt*16+lr)*VTP + ks*32 + kg*8];
        acc[dt] = __builtin_amdgcn_mfma_f32_16x16x32_bf16(pf, vf, acc[dt], 0,0,0);
      }
    }

    #pragma unroll
    for (int dt = 0; dt < 4; dt++)
      #pragma unroll
      for (int j = 0; j < 4; j++) {
        int tq = q0 + kg*4 + j;
        if (tq < TT)
          ob[((size_t)(b*TT + tq))*CDIM + h*HD + dt*16 + lr] = f2bf(acc[dt][j]);
      }
  }
}

// ---------------------------------------------------------------- final2 (cls row)
__global__ __launch_bounds__(256) void final2_kernel(
    const float* __restrict__ csb, void* __restrict__ outv, const int* __restrict__ flag)
{
  const int f = *flag;
  int i = blockIdx.x*256 + threadIdx.x;
  if (i >= BATCH*CDIM) return;
  int b = i / CDIM, c = i - b*CDIM;
  const float* p = csb + (size_t)b*13*CDIM + c;
  float s = 0.f;
  #pragma unroll
  for (int j = 1; j <= 12; j++) s += p[(size_t)j*CDIM];
  float v = p[0] + s * (1.0f/12.0f);
  size_t oi = ((size_t)b*NTOK)*CDIM + c;
  if (f) ((u16*)outv)[oi] = f2bf(v);
  else   ((float*)outv)[oi] = v;
}

// ---------------------------------------------------------------- launch
extern "C" void kernel_launch(void* const* d_in, const int* in_sizes, int n_in,
                              void* d_out, int out_size, void* d_ws, size_t ws_size,
                              hipStream_t stream)
{
  char* ws = (char*)d_ws;
  size_t off = 0;
  auto alloc = [&](size_t bytes)->void* {
    void* p = ws + off; off += (bytes + 255) & ~(size_t)255; return p;
  };

  int* flag = (int*)alloc(256);

  u16* cin[10];
  for (int i = 0; i < 10; i++) cin[i] = (u16*)alloc((size_t)in_sizes[i]*2);

  u16* qkvT  = (u16*)alloc((size_t)3*CDIM*CDIM*2);        // 2304 x 768
  u16* projT = (u16*)alloc((size_t)CDIM*CDIM*2);          // 768 x 768
  u16* htb_  = (u16*)alloc((size_t)BATCH*NH*CDIM*2);      // (B*H) x 768
  float* mbuf = (float*)alloc((size_t)BATCH*CDIM*4);      // per-batch col means
  u16* qkvo  = (u16*)alloc((size_t)GM*NQKV*2);            // (B*T) x 2304 (v third unused)
  u16* vb    = (u16*)alloc((size_t)BATCH*NH*HD*VTP*2);    // (B,H,HD,VTP)
  float* csb = (float*)alloc((size_t)BATCH*13*CDIM*4);    // cls side buffer
  u16* ao    = cin[0];   // alias: x dead after gemm<0>; cin[1] never used

  detect_kernel<<<1, 64, 0, stream>>>((const u16*)d_in[0], flag);

  CA ca;
  for (int i = 0; i < 10; i++) { ca.in[i] = d_in[i]; ca.out[i] = cin[i]; ca.n[i] = in_sizes[i]; }
  ca.out[1] = vb; ca.n[1] = BATCH*NH*HD;   // seg 1 repurposed: zero vb pad rows
  convert_all_kernel<<<dim3(256, 10), 256, 0, stream>>>(ca, flag);

  transpose2_kernel<<<576, 256, 0, stream>>>(d_in[1], d_in[3], qkvT, projT, flag);
  mean_kernel<<<dim3(BATCH, 3), 256, 0, stream>>>(cin[0], d_in[0], mbuf, flag);
  htmm_kernel<<<dim3(BATCH, NH), 256, 0, stream>>>(mbuf, cin[5], cin[6], cin[7], cin[8], cin[9], htb_);
  gemm_kernel<0><<<dim3(NQKV/128, (GM+127)/128), 256, 0, stream>>>(
      cin[0], d_in[0], htb_, qkvT, cin[2], qkvo, vb, nullptr, nullptr, flag);
  attn_kernel<<<BATCH*NH, 256, 0, stream>>>(qkvo, vb, ao);
  gemm_kernel<1><<<dim3(CDIM/128, (GM+127)/128), 256, 0, stream>>>(
      ao, nullptr, nullptr, projT, cin[4], nullptr, nullptr, d_out, csb, flag);
  final2_kernel<<<(BATCH*CDIM+255)/256, 256, 0, stream>>>(csb, d_out, flag);
}

// Round 19
// 235.690 us; speedup vs baseline: 1.1697x; 1.0359x over previous
//
#include <hip/hip_runtime.h>
#include <cstdint>
#include <cstddef>

typedef unsigned short u16;
typedef __attribute__((ext_vector_type(8))) __bf16 bf16x8;
typedef __attribute__((ext_vector_type(4))) unsigned short u16x4;
typedef __attribute__((ext_vector_type(8))) unsigned short u16x8;
typedef __attribute__((ext_vector_type(4))) float f32x4;

#define NTOK 197
#define TT   209
#define CDIM 768
#define NH   12
#define HD   64
#define BATCH 64
#define GM (BATCH*TT)   // 13376
#define VTP 224         // padded T stride for transposed V
#define NQKV 2304

__device__ __forceinline__ float bf2f(u16 u){ return __uint_as_float(((unsigned)u)<<16); }
__device__ __forceinline__ u16 f2bf(float f){
  unsigned x = __float_as_uint(f);
  return (u16)((x + 0x7FFFu + ((x>>16)&1u)) >> 16);   // RNE; inputs finite
}

__device__ __forceinline__ void gll16(const void* g, void* l){
  __builtin_amdgcn_global_load_lds((const __attribute__((address_space(1))) void*)g,
                                   (__attribute__((address_space(3))) void*)l,
                                   16, 0, 0);
}

__device__ __forceinline__ float wsum64(float v){
  #pragma unroll
  for (int o = 32; o > 0; o >>= 1) v += __shfl_xor(v, o, 64);
  return v;
}

// ---------------------------------------------------------------- dtype detect
__global__ __launch_bounds__(64) void detect_kernel(const u16* __restrict__ x, int* flag){
  const int lane = threadIdx.x;
  float mx = 0.f;
  #pragma unroll
  for (int i = 0; i < 16; i++) {
    float v = fabsf(bf2f(x[i*64 + lane]));
    if (!(v < 1e30f)) v = 1e30f;
    mx = fmaxf(mx, v);
  }
  #pragma unroll
  for (int o = 32; o; o >>= 1) mx = fmaxf(mx, __shfl_xor(mx, o, 64));
  if (lane == 0) *flag = (mx < 1e5f) ? 1 : 0;   // 1 = device buffers are bf16
}

// ---------------------------------------------------------------- fused convert
struct CA { const void* in[10]; void* out[10]; int n[10]; };
__global__ __launch_bounds__(256) void convert_all_kernel(CA a, const int* __restrict__ flag){
  const int seg = blockIdx.y;
  if (seg == 1 || seg == 3) return;
  const int f = *flag;
  if (seg == 0 && f) return;
  const int n = a.n[seg];
  const int n4 = n >> 2;
  u16* out = (u16*)a.out[seg];
  if (f) {
    const u16x4* in = (const u16x4*)a.in[seg];
    for (int i = blockIdx.x*256 + threadIdx.x; i < n4; i += gridDim.x*256)
      ((u16x4*)out)[i] = in[i];
  } else {
    const f32x4* in = (const f32x4*)a.in[seg];
    for (int i = blockIdx.x*256 + threadIdx.x; i < n4; i += gridDim.x*256){
      f32x4 v = in[i];
      u16x4 o;
      #pragma unroll
      for (int j=0;j<4;j++) o[j] = f2bf(v[j]);
      ((u16x4*)out)[i] = o;
    }
  }
  if (blockIdx.x == 0 && (int)threadIdx.x < (n & 3)) {
    int i = (n4 << 2) + threadIdx.x;
    out[i] = f ? ((const u16*)a.in[seg])[i] : f2bf(((const float*)a.in[seg])[i]);
  }
}

// ---------------------------------------------------------------- fused transpose (+convert)
__global__ __launch_bounds__(256) void transpose2_kernel(
    const void* __restrict__ w1, const void* __restrict__ w2,
    u16* __restrict__ o1, u16* __restrict__ o2, const int* __restrict__ flag)
{
  __shared__ u16 lds[64][66];
  const int f = *flag;
  int bid = blockIdx.x;
  const void* in; u16* out; int K, N, tx, ty;
  if (bid < 432) { in = w1; out = o1; K = CDIM; N = NQKV; tx = bid % 36; ty = bid / 36; }
  else { bid -= 432; in = w2; out = o2; K = CDIM; N = CDIM; tx = bid % 12; ty = bid / 12; }
  const int n0 = tx*64, k0 = ty*64;
  const int c = threadIdx.x & 63, r0 = threadIdx.x >> 6;
  #pragma unroll
  for (int i=0;i<16;i++) {
    int r = i*4 + r0;
    size_t idx = (size_t)(k0+r)*N + n0 + c;
    lds[r][c] = f ? ((const u16*)in)[idx] : f2bf(((const float*)in)[idx]);
  }
  __syncthreads();
  #pragma unroll
  for (int i=0;i<16;i++) {
    int r = i*4 + r0;
    out[(size_t)(n0+r)*K + k0 + c] = lds[c][r];
  }
}

// ---------------------------------------------------------------- mean (ht phase 1)
__global__ __launch_bounds__(256) void mean_kernel(
    const u16* __restrict__ xc, const void* __restrict__ xr,
    float* __restrict__ mbuf, const int* __restrict__ flag)
{
  const int b = blockIdx.x, s = blockIdx.y;
  const int tid = threadIdx.x;
  const int f = *flag;
  const u16* x = f ? (const u16*)xr : xc;
  const u16* xp = x + (size_t)b*NTOK*CDIM + s*256 + tid;
  float cs = 0.f;
  for (int n = 0; n < NTOK; n++) cs += bf2f(xp[(size_t)n*CDIM]);
  mbuf[(size_t)b*CDIM + s*256 + tid] = cs * (1.0f/(float)NTOK);
}

// ---------------------------------------------------------------- ht matvec+LN (phase 2)
__global__ __launch_bounds__(256) void htmm_kernel(
    const float* __restrict__ mbuf,
    const u16* __restrict__ htw, const u16* __restrict__ htb,
    const u16* __restrict__ lng, const u16* __restrict__ lnb,
    const u16* __restrict__ pos, u16* __restrict__ ht)
{
  const int b = blockIdx.x, h = blockIdx.y;
  const int tid = threadIdx.x;
  __shared__ float msh[64];
  if (tid < 64) msh[tid] = mbuf[(size_t)b*CDIM + h*HD + tid];
  __syncthreads();

  float v0 = bf2f(htb[tid]), v1 = bf2f(htb[tid+256]), v2 = bf2f(htb[tid+512]);
  for (int d = 0; d < HD; d++) {
    const float md = msh[d];
    const u16* wr = htw + (size_t)d*CDIM;
    v0 += md * bf2f(wr[tid]);
    v1 += md * bf2f(wr[tid+256]);
    v2 += md * bf2f(wr[tid+512]);
  }
  const float gam = bf2f(lng[tid & 63]), bet = bf2f(lnb[tid & 63]);
  float vv[3] = {v0, v1, v2};
  #pragma unroll
  for (int ch = 0; ch < 3; ch++) {
    int c = ch*256 + tid;
    float mu = wsum64(vv[ch]) * (1.0f/(float)HD);
    float dv = vv[ch] - mu;
    float var = wsum64(dv*dv) * (1.0f/(float)HD);
    float y = dv * rsqrtf(var + 1e-5f) * gam + bet;
    float ge = 0.5f * y * (1.0f + erff(y * 0.70710678118654752f));
    float o = ge + bf2f(pos[h*CDIM + c]);
    ht[((size_t)(b*NH + h))*CDIM + c] = f2bf(o);
  }
}

// ---------------------------------------------------------------- GEMM
// R15/R17-proven: 128x128 tile, BK=32, 4 waves, ring-5 buffers (80KB), depth-3
// prefetch, single barrier/iter, counted vmcnt, XOR seg swizzle, m204 remap.
// MODE 0: contiguous full-row qkvo write (78µs measured).
template<int MODE>
__global__ __launch_bounds__(256, 2) void gemm_kernel(
    const u16* __restrict__ A0c, const void* __restrict__ A0r,
    const u16* __restrict__ A1,
    const u16* __restrict__ Bt, const u16* __restrict__ bias,
    u16* __restrict__ qout,
    void* __restrict__ outv, float* __restrict__ csb, const int* __restrict__ flag)
{
  const int tid = threadIdx.x;
  const int lane = tid & 63;
  const int w = tid >> 6;
  const int wm = w >> 1, wn = w & 1;
  const int lr = lane & 15, kg = lane >> 4;

  const int NT = gridDim.x;
  const int nwg = NT * gridDim.y;
  const int orig = blockIdx.y * NT + blockIdx.x;
  const int xcd = orig & 7, sIdx = orig >> 3;
  const int q = nwg >> 3, r = nwg & 7;
  const int wg = ((xcd < r) ? xcd*(q+1) : r*(q+1) + (xcd-r)*q) + sIdx;
  const int tm = wg / NT, tn = wg - tm*NT;

  __shared__ __align__(16) u16 As[5][4096];   // [buf][row*32 + seg*8 + e]
  __shared__ __align__(16) u16 Bs[5][4096];

  const int f = *flag;
  const u16* A0 = (MODE == 0) ? (f ? (const u16*)A0r : A0c) : A0c;

  f32x4 acc[4][4];
  #pragma unroll
  for (int i=0;i<4;i++)
    #pragma unroll
    for (int j=0;j<4;j++) acc[i][j] = (f32x4){0.f,0.f,0.f,0.f};

  const u16* garow[2];
  const u16* gbrow[2];
  #pragma unroll
  for (int i=0;i<2;i++){
    int row = (i*4 + w)*16 + (lane >> 2);
    int rr = tm*128 + row; if (rr > GM-1) rr = GM-1;
    if (MODE == 0) {
      int bb = rr / TT; int t = rr - bb*TT;
      garow[i] = (t < NTOK) ? (A0 + (size_t)(bb*NTOK + t)*CDIM)
                            : (A1 + (size_t)(bb*NH + (t - NTOK))*CDIM);
    } else {
      garow[i] = A0 + (size_t)rr*CDIM;
    }
    gbrow[i] = Bt + (size_t)(tn*128 + row)*CDIM;
  }
  const int gseg = (lane & 3) ^ ((lane >> 3) & 3);   // = seg ^ ((row>>1)&3)

#define STAGE(kt_, bf_) do { \
    const int ko_ = (kt_)*32 + gseg*8; \
    gll16(garow[0] + ko_, (void*)&As[bf_][(0*4+w)*512]); \
    gll16(garow[1] + ko_, (void*)&As[bf_][(1*4+w)*512]); \
    gll16(gbrow[0] + ko_, (void*)&Bs[bf_][(0*4+w)*512]); \
    gll16(gbrow[1] + ko_, (void*)&Bs[bf_][(1*4+w)*512]); \
  } while(0)

  STAGE(0, 0);
  STAGE(1, 1);
  STAGE(2, 2);

  const int spA = kg ^ ((lr >> 1) & 3);   // read-side swizzled segment

  #pragma unroll
  for (int kt = 0; kt < 24; kt++) {
    const int cb = kt % 5;
    if (kt < 21) {
      STAGE(kt+3, (kt+3)%5);
      asm volatile("s_waitcnt vmcnt(12)" ::: "memory");   // stage kt drained
    } else if (kt == 21) {
      asm volatile("s_waitcnt vmcnt(8)" ::: "memory");
    } else if (kt == 22) {
      asm volatile("s_waitcnt vmcnt(4)" ::: "memory");
    } else {
      asm volatile("s_waitcnt vmcnt(0)" ::: "memory");
    }
    __builtin_amdgcn_s_barrier();     // single barrier/iter (ring-5 WAR proof)

    bf16x8 av[4], bv[4];
    #pragma unroll
    for (int mi=0; mi<4; mi++)
      av[mi] = *(const bf16x8*)&As[cb][(wm*64+mi*16+lr)*32 + spA*8];
    #pragma unroll
    for (int ni=0; ni<4; ni++)
      bv[ni] = *(const bf16x8*)&Bs[cb][(wn*64+ni*16+lr)*32 + spA*8];
    #pragma unroll
    for (int mi=0; mi<4; mi++)
      #pragma unroll
      for (int ni=0; ni<4; ni++)
        acc[mi][ni] = __builtin_amdgcn_mfma_f32_16x16x32_bf16(av[mi], bv[ni], acc[mi][ni], 0,0,0);
  }
#undef STAGE

  #pragma unroll
  for (int mi=0; mi<4; mi++){
    const int rb = tm*128 + wm*64 + mi*16 + kg*4;
    #pragma unroll
    for (int ni=0; ni<4; ni++){
      const int c = tn*128 + wn*64 + ni*16 + lr;
      const float bs = bf2f(bias[c]);
      if (MODE == 0) {
        #pragma unroll
        for (int j=0;j<4;j++){
          int rr = rb + j;
          if (rr < GM) qout[(size_t)rr*NQKV + c] = f2bf(acc[mi][ni][j] + bs);
        }
      } else {
        #pragma unroll
        for (int j=0;j<4;j++){
          int rr = rb + j;
          if (rr < GM) {
            int bb = rr / TT; int t = rr - bb*TT;
            float v = acc[mi][ni][j] + bs;
            if (t >= 1 && t < NTOK) {
              size_t oi = ((size_t)(bb*NTOK + t))*CDIM + c;
              if (f) ((u16*)outv)[oi] = f2bf(v);
              else   ((float*)outv)[oi] = v;
            } else {
              int idx = (t == 0) ? 0 : (t - NTOK + 1);   // 0, 1..12
              csb[((size_t)(bb*13 + idx))*CDIM + c] = v;
            }
          }
        }
      }
    }
  }
}

// ---------------------------------------------------------------- vtrans
// (b,h): v slice of qkvo -> vb (b,h,d,VTP), zero-padded t in [TT,VTP).
__global__ __launch_bounds__(256) void vtrans_kernel(
    const u16* __restrict__ qkvo, u16* __restrict__ vb)
{
  __shared__ u16 lds[64][66];
  const int tt0 = blockIdx.x*64;
  const int bh = blockIdx.y;
  const int b = bh / NH, h = bh - b*NH;
  const int c = threadIdx.x & 63, r0 = threadIdx.x >> 6;
  #pragma unroll
  for (int i=0;i<16;i++) {
    int t = tt0 + i*4 + r0;
    u16 v = 0;
    if (t < TT) v = qkvo[(size_t)(b*TT + t)*NQKV + 1536 + h*64 + c];
    lds[i*4+r0][c] = v;
  }
  __syncthreads();
  #pragma unroll
  for (int i=0;i<16;i++) {
    int d = i*4 + r0;
    int t = tt0 + c;
    if (t < VTP) vb[((size_t)(bh)*HD + d)*VTP + t] = lds[c][d];
  }
}

// ---------------------------------------------------------------- attention v2
// One block (4 waves) per (b,h). K staged once into LDS [224][72] (zero-pad,
// 2-way-free bank pattern), one __syncthreads, then each wave independently
// processes q-chunks ck = w, w+4, ... with in-register softmax (swapped QK^T),
// per-wave P LDS, PV from transposed-V global. No further barriers.
__global__ __launch_bounds__(256) void attn_kernel(
    const u16* __restrict__ qkvo, const u16* __restrict__ vt, u16* __restrict__ ob)
{
  __shared__ __align__(16) u16 Kl[224*72];      // 32256 B
  __shared__ __align__(16) u16 P[4][7*16*32];   // 28672 B
  const int tid = threadIdx.x;
  const int lane = tid & 63;
  const int w = tid >> 6;
  const int lr = lane & 15, kg = lane >> 4;

  const int bh = blockIdx.x;
  const int b = bh / NH, h = bh - b*NH;

  const u16* qg  = qkvo + (size_t)(b*TT)*NQKV + h*64;
  const u16* kgp = qg + CDIM;
  const u16* vg  = vt + (size_t)bh*HD*VTP;

  for (int s = tid; s < 224*8; s += 256) {
    int kc = s >> 3, seg = s & 7;
    uint4 val = make_uint4(0,0,0,0);
    if (kc < TT) val = *(const uint4*)&kgp[(size_t)kc*NQKV + seg*8];
    *(uint4*)&Kl[kc*72 + seg*8] = val;
  }
  __syncthreads();

  u16* Pw = &P[w][0];
  for (int ck = w; ck < 14; ck += 4) {
    const int q0 = ck*16;
    int qrow = q0 + lr; if (qrow > TT-1) qrow = TT-1;
    const bf16x8 qf0 = *(const bf16x8*)&qg[(size_t)qrow*NQKV + kg*8];
    const bf16x8 qf1 = *(const bf16x8*)&qg[(size_t)qrow*NQKV + 32 + kg*8];

    f32x4 sv[14];
    #pragma unroll
    for (int kt = 0; kt < 14; kt++) {
      bf16x8 kf0 = *(const bf16x8*)&Kl[(kt*16+lr)*72 + kg*8];
      bf16x8 kf1 = *(const bf16x8*)&Kl[(kt*16+lr)*72 + 32 + kg*8];
      f32x4 sa = {0.f,0.f,0.f,0.f};
      sa = __builtin_amdgcn_mfma_f32_16x16x32_bf16(kf0, qf0, sa, 0,0,0);
      sa = __builtin_amdgcn_mfma_f32_16x16x32_bf16(kf1, qf1, sa, 0,0,0);
      sv[kt] = sa;
    }

    float m = -3.0e38f;
    #pragma unroll
    for (int kt = 0; kt < 13; kt++)
      #pragma unroll
      for (int j=0;j<4;j++){ sv[kt][j] *= 0.125f; m = fmaxf(m, sv[kt][j]); }
    #pragma unroll
    for (int j=0;j<4;j++){
      sv[13][j] *= 0.125f;
      if (208 + kg*4 + j < TT) m = fmaxf(m, sv[13][j]);
    }
    m = fmaxf(m, __shfl_xor(m, 16, 64));
    m = fmaxf(m, __shfl_xor(m, 32, 64));

    float ssum = 0.f;
    #pragma unroll
    for (int kt = 0; kt < 13; kt++)
      #pragma unroll
      for (int j=0;j<4;j++){ float e = __expf(sv[kt][j] - m); sv[kt][j] = e; ssum += e; }
    #pragma unroll
    for (int j=0;j<4;j++){
      float e = (208 + kg*4 + j < TT) ? __expf(sv[13][j] - m) : 0.f;
      sv[13][j] = e; ssum += e;
    }
    ssum += __shfl_xor(ssum, 16, 64);
    ssum += __shfl_xor(ssum, 32, 64);
    const float inv = 1.0f / ssum;

    #pragma unroll
    for (int kt = 0; kt < 14; kt++) {
      u16x4 pk;
      #pragma unroll
      for (int j=0;j<4;j++) pk[j] = f2bf(sv[kt][j] * inv);
      *(u16x4*)&Pw[(kt>>1)*512 + lr*32 + (kt&1)*16 + kg*4] = pk;
    }

    f32x4 acc[4];
    #pragma unroll
    for (int dt=0; dt<4; dt++) acc[dt] = (f32x4){0.f,0.f,0.f,0.f};
    #pragma unroll
    for (int ks = 0; ks < 7; ks++) {
      bf16x8 pf = *(const bf16x8*)&Pw[ks*512 + lr*32 + kg*8];
      #pragma unroll
      for (int dt = 0; dt < 4; dt++) {
        bf16x8 vf = *(const bf16x8*)&vg[(dt*16+lr)*VTP + ks*32 + kg*8];
        acc[dt] = __builtin_amdgcn_mfma_f32_16x16x32_bf16(pf, vf, acc[dt], 0,0,0);
      }
    }

    #pragma unroll
    for (int dt = 0; dt < 4; dt++)
      #pragma unroll
      for (int j = 0; j < 4; j++) {
        int tq = q0 + kg*4 + j;
        if (tq < TT)
          ob[((size_t)(b*TT + tq))*CDIM + h*HD + dt*16 + lr] = f2bf(acc[dt][j]);
      }
  }
}

// ---------------------------------------------------------------- final2 (cls row)
__global__ __launch_bounds__(256) void final2_kernel(
    const float* __restrict__ csb, void* __restrict__ outv, const int* __restrict__ flag)
{
  const int f = *flag;
  int i = blockIdx.x*256 + threadIdx.x;
  if (i >= BATCH*CDIM) return;
  int b = i / CDIM, c = i - b*CDIM;
  const float* p = csb + (size_t)b*13*CDIM + c;
  float s = 0.f;
  #pragma unroll
  for (int j = 1; j <= 12; j++) s += p[(size_t)j*CDIM];
  float v = p[0] + s * (1.0f/12.0f);
  size_t oi = ((size_t)b*NTOK)*CDIM + c;
  if (f) ((u16*)outv)[oi] = f2bf(v);
  else   ((float*)outv)[oi] = v;
}

// ---------------------------------------------------------------- launch
extern "C" void kernel_launch(void* const* d_in, const int* in_sizes, int n_in,
                              void* d_out, int out_size, void* d_ws, size_t ws_size,
                              hipStream_t stream)
{
  char* ws = (char*)d_ws;
  size_t off = 0;
  auto alloc = [&](size_t bytes)->void* {
    void* p = ws + off; off += (bytes + 255) & ~(size_t)255; return p;
  };

  int* flag = (int*)alloc(256);

  u16* cin[10];
  for (int i = 0; i < 10; i++) cin[i] = (u16*)alloc((size_t)in_sizes[i]*2);

  u16* qkvT  = (u16*)alloc((size_t)3*CDIM*CDIM*2);        // 2304 x 768
  u16* projT = (u16*)alloc((size_t)CDIM*CDIM*2);          // 768 x 768
  u16* htb_  = (u16*)alloc((size_t)BATCH*NH*CDIM*2);      // (B*H) x 768
  float* mbuf = (float*)alloc((size_t)BATCH*CDIM*4);      // per-batch col means
  u16* qkvo  = (u16*)alloc((size_t)GM*NQKV*2);            // (B*T) x 2304
  u16* vb    = (u16*)alloc((size_t)BATCH*NH*HD*VTP*2);    // (B,H,HD,VTP)
  float* csb = (float*)alloc((size_t)BATCH*13*CDIM*4);    // cls side buffer
  u16* ao    = cin[0];   // alias: x dead after gemm<0>; cin[1] never used

  detect_kernel<<<1, 64, 0, stream>>>((const u16*)d_in[0], flag);

  CA ca;
  for (int i = 0; i < 10; i++) { ca.in[i] = d_in[i]; ca.out[i] = cin[i]; ca.n[i] = in_sizes[i]; }
  convert_all_kernel<<<dim3(256, 10), 256, 0, stream>>>(ca, flag);

  transpose2_kernel<<<576, 256, 0, stream>>>(d_in[1], d_in[3], qkvT, projT, flag);
  mean_kernel<<<dim3(BATCH, 3), 256, 0, stream>>>(cin[0], d_in[0], mbuf, flag);
  htmm_kernel<<<dim3(BATCH, NH), 256, 0, stream>>>(mbuf, cin[5], cin[6], cin[7], cin[8], cin[9], htb_);
  gemm_kernel<0><<<dim3(NQKV/128, (GM+127)/128), 256, 0, stream>>>(
      cin[0], d_in[0], htb_, qkvT, cin[2], qkvo, nullptr, nullptr, flag);
  vtrans_kernel<<<dim3(4, BATCH*NH), 256, 0, stream>>>(qkvo, vb);
  attn_kernel<<<BATCH*NH, 256, 0, stream>>>(qkvo, vb, ao);
  gemm_kernel<1><<<dim3(CDIM/128, (GM+127)/128), 256, 0, stream>>>(
      ao, nullptr, nullptr, projT, cin[4], nullptr, d_out, csb, flag);
  final2_kernel<<<(BATCH*CDIM+255)/256, 256, 0, stream>>>(csb, d_out, flag);
}